// Round 1
// baseline (411.871 us; speedup 1.0000x reference)
//
#include <hip/hip_runtime.h>

// LIF neuron: v' = v + (i - v)/10 ; spike = v' >= 1 ; reset to 0.
// One thread per (b, n) chain; serial over T with register double-buffered
// prefetch (U=10) to hide HBM latency at low occupancy (2 waves/CU).

constexpr int B = 32;
constexpr int T = 1000;
constexpr int N = 1024;
constexpr int U = 10;          // prefetch depth; T % U == 0

__global__ __launch_bounds__(64) void lif_kernel(
    const float* __restrict__ in,   // [B, T, N]
    const float* __restrict__ v0,   // [B, N]
    float* __restrict__ spk,        // [B, T, N]
    float* __restrict__ vol)        // [B, T, N]
{
    const int idx = blockIdx.x * 64 + threadIdx.x;   // 0 .. B*N-1
    const int b = idx >> 10;                          // N == 1024
    const int n = idx & (N - 1);
    const size_t base = (size_t)b * T * N + n;

    const float* ip = in  + base;
    float*       sp = spk + base;
    float*       vp = vol + base;

    float v = v0[idx];

    float cur[U];
    #pragma unroll
    for (int j = 0; j < U; ++j) cur[j] = ip[(size_t)j * N];

    for (int t0 = 0; t0 < T; t0 += U) {
        float nxt[U];
        if (t0 + U < T) {
            #pragma unroll
            for (int j = 0; j < U; ++j)
                nxt[j] = ip[(size_t)(t0 + U + j) * N];
        }

        #pragma unroll
        for (int j = 0; j < U; ++j) {
            // Exactly mirrors: v = v + ((-(v - 0) + i)/10.0)*1.0  (IEEE fp32 div)
            v = v + (cur[j] - v) / 10.0f;
            const bool fire = (v >= 1.0f);
            sp[(size_t)(t0 + j) * N] = fire ? 1.0f : 0.0f;
            v = fire ? 0.0f : v;                 // v*(1-s) + 0*s, exact
            vp[(size_t)(t0 + j) * N] = v;
        }

        #pragma unroll
        for (int j = 0; j < U; ++j) cur[j] = nxt[j];
    }
}

extern "C" void kernel_launch(void* const* d_in, const int* in_sizes, int n_in,
                              void* d_out, int out_size, void* d_ws, size_t ws_size,
                              hipStream_t stream) {
    const float* in = (const float*)d_in[0];   // [B, T, N]
    const float* v0 = (const float*)d_in[1];   // [B, N]
    float* spk = (float*)d_out;                       // [B, T, N]
    float* vol = (float*)d_out + (size_t)B * T * N;   // [B, T, N]

    const int threads = 64;
    const int blocks  = (B * N) / threads;     // 512 blocks -> ~2 waves/CU on 256 CUs
    lif_kernel<<<blocks, threads, 0, stream>>>(in, v0, spk, vol);
}

// Round 2
// 361.981 us; speedup vs baseline: 1.1378x; 1.1378x over previous
//
#include <hip/hip_runtime.h>

// LIF neuron: v' = v + (i - v)/10 ; spike = v' >= 1 ; reset to 0.
// One thread per (b, n) chain; serial over T.
// Key structure (round 2): stores are decoupled from the recurrence via
// per-step register buffers (sb/vb) so the loop-carried `v` register never
// waits on store completion (in-order vmcnt retirement); loads are U=20-deep
// ping-pong double-buffered to put ~2.6 MB in flight device-wide.

constexpr int B = 32;
constexpr int T = 1000;
constexpr int N = 1024;
constexpr int U = 20;          // block depth; T % (2*U) == 0
constexpr int NBLK = T / U;    // 50 (even)

__device__ __forceinline__ void lif_steps(const float (&buf)[U], float& v,
                                          float* __restrict__ sp,
                                          float* __restrict__ vp, int t0)
{
    float sb[U], vb[U];
    #pragma unroll
    for (int j = 0; j < U; ++j) {
        // Exactly mirrors: v = v + ((-(v - 0) + i)/10.0)*1.0  (IEEE fp32 div)
        float nv = v + (buf[j] - v) / 10.0f;
        const bool fire = (nv >= 1.0f);
        sb[j] = fire ? 1.0f : 0.0f;
        nv = fire ? 0.0f : nv;     // v*(1-s) + 0*s, exact for s in {0,1}
        vb[j] = nv;
        v = nv;
    }
    // Burst the 2U stores from dedicated registers (no dependence on `v`).
    #pragma unroll
    for (int j = 0; j < U; ++j) {
        sp[(size_t)(t0 + j) * N] = sb[j];
        vp[(size_t)(t0 + j) * N] = vb[j];
    }
}

__global__ __launch_bounds__(64) void lif_kernel(
    const float* __restrict__ in,   // [B, T, N]
    const float* __restrict__ v0,   // [B, N]
    float* __restrict__ spk,        // [B, T, N]
    float* __restrict__ vol)        // [B, T, N]
{
    const int idx = blockIdx.x * 64 + threadIdx.x;   // 0 .. B*N-1
    const int b = idx >> 10;                          // N == 1024
    const int n = idx & (N - 1);
    const size_t base = (size_t)b * T * N + n;

    const float* ip = in  + base;
    float*       sp = spk + base;
    float*       vp = vol + base;

    float v = v0[idx];

    float bufA[U], bufB[U];
    #pragma unroll
    for (int j = 0; j < U; ++j) bufA[j] = ip[(size_t)j * N];

    for (int blk = 0; blk < NBLK; blk += 2) {
        const int tA = blk * U;
        const int tB = tA + U;          // always < T (NBLK even)
        const int tC = tA + 2 * U;

        #pragma unroll
        for (int j = 0; j < U; ++j) bufB[j] = ip[(size_t)(tB + j) * N];

        lif_steps(bufA, v, sp, vp, tA);

        if (tC < T) {
            #pragma unroll
            for (int j = 0; j < U; ++j) bufA[j] = ip[(size_t)(tC + j) * N];
        }

        lif_steps(bufB, v, sp, vp, tB);
    }
}

extern "C" void kernel_launch(void* const* d_in, const int* in_sizes, int n_in,
                              void* d_out, int out_size, void* d_ws, size_t ws_size,
                              hipStream_t stream) {
    const float* in = (const float*)d_in[0];   // [B, T, N]
    const float* v0 = (const float*)d_in[1];   // [B, N]
    float* spk = (float*)d_out;                       // [B, T, N]
    float* vol = (float*)d_out + (size_t)B * T * N;   // [B, T, N]

    const int threads = 64;
    const int blocks  = (B * N) / threads;     // 512 blocks -> 2 waves/CU on 256 CUs
    lif_kernel<<<blocks, threads, 0, stream>>>(in, v0, spk, vol);
}